// Round 1
// baseline (530.634 us; speedup 1.0000x reference)
//
#include <hip/hip_runtime.h>
#include <cstdint>

// Problem constants (x: [64, 768, 28, 28] fp32)
#define B_   64
#define C_   768
#define HID_ 192
#define HW_  784                 // 28*28
#define NCHAN (B_ * C_)          // 49152
#define V4PC (HW_ / 4)           // 196 float4 per channel

typedef float vfloat4 __attribute__((ext_vector_type(4)));

#define PF_BLOCKS 2048
#define CH_PER_BLOCK (NCHAN / PF_BLOCKS)      // 24 channels per block
#define BLK_PER_BATCH (PF_BLOCKS / B_)        // 32 blocks cover one batch image

// ---------- Kernel 1: fused global-avg-pool + FC1/FC2 (last-arriver) ----------
// 2048 blocks x 256 threads. Each block pools 24 channels (all within ONE batch,
// since 32 blocks = exactly one batch). The last block of a batch to finish
// (agent-scope fetch_add, release; winner does an acquire load) computes the
// squeeze-excitation FC stack for that batch inline. Kills the standalone
// 64-block latency-bound fc dispatch; its cost overlaps other batches' pooling.
__global__ __launch_bounds__(256, 4) void poolfc_kernel(
    const float* __restrict__ x,
    const float* __restrict__ w1, const float* __restrict__ b1,
    const float* __restrict__ w2, const float* __restrict__ b2,
    float* __restrict__ pooled, float* __restrict__ s_out,
    unsigned int* __restrict__ done)
{
    const int bid  = blockIdx.x;
    const int t    = threadIdx.x;
    const int wv   = t >> 6;
    const int lane = t & 63;
    const int b    = bid / BLK_PER_BATCH;     // batch this block belongs to

    // ---- pool phase: wave-per-channel, 6 channels per wave ----
    for (int i = wv; i < CH_PER_BLOCK; i += 4) {
        const int ch = bid * CH_PER_BLOCK + i;
        const vfloat4* p = (const vfloat4*)(x + (size_t)ch * HW_);
        vfloat4 v0 = p[lane];
        vfloat4 v1 = p[lane + 64];
        vfloat4 v2 = p[lane + 128];
        float sum = (v0.x + v0.y + v0.z + v0.w)
                  + (v1.x + v1.y + v1.z + v1.w)
                  + (v2.x + v2.y + v2.z + v2.w);
        if (lane < V4PC - 192) {              // 4 tail float4 (indices 192..195)
            vfloat4 v3 = p[lane + 192];
            sum += v3.x + v3.y + v3.z + v3.w;
        }
        #pragma unroll
        for (int off = 32; off > 0; off >>= 1) sum += __shfl_down(sum, off, 64);
        if (lane == 0) pooled[ch] = sum * (1.0f / (float)HW_);
    }
    __syncthreads();   // drains each wave's vmcnt -> block's pooled stores are in L2

    __shared__ int winner_s;
    if (t == 0) {
        // release: publishes this block's pooled[] (incl. L2 writeback, cross-XCD)
        unsigned old = __hip_atomic_fetch_add(&done[b], 1u,
                                              __ATOMIC_RELEASE,
                                              __HIP_MEMORY_SCOPE_AGENT);
        winner_s = (old == BLK_PER_BATCH - 1);
        if (winner_s) {
            // acquire: pairs with the other 31 blocks' releases; invalidates L1/L2
            (void)__hip_atomic_load(&done[b], __ATOMIC_ACQUIRE,
                                    __HIP_MEMORY_SCOPE_AGENT);
        }
    }
    __syncthreads();
    if (!winner_s) return;

    // ---- fc phase: this block owns batch b ----
    __shared__ float sp[C_];
    __shared__ float sh[HID_];
    for (int i = t; i < C_; i += 256) sp[i] = pooled[b * C_ + i];
    __syncthreads();

    if (t < HID_) {
        const vfloat4* row = (const vfloat4*)(w1 + (size_t)t * C_);
        float a0 = 0.f, a1 = 0.f, a2 = 0.f, a3 = 0.f;
        #pragma unroll 2
        for (int f = 0; f < C_ / 16; ++f) {   // 48 iters x 4 float4
            vfloat4 u0 = row[4*f+0], u1 = row[4*f+1], u2 = row[4*f+2], u3 = row[4*f+3];
            const float* pp = &sp[16 * f];    // uniform address -> LDS broadcast
            a0 += u0.x*pp[ 0] + u0.y*pp[ 1] + u0.z*pp[ 2] + u0.w*pp[ 3];
            a1 += u1.x*pp[ 4] + u1.y*pp[ 5] + u1.z*pp[ 6] + u1.w*pp[ 7];
            a2 += u2.x*pp[ 8] + u2.y*pp[ 9] + u2.z*pp[10] + u2.w*pp[11];
            a3 += u3.x*pp[12] + u3.y*pp[13] + u3.z*pp[14] + u3.w*pp[15];
        }
        float h = a0 + a1 + a2 + a3 + b1[t];
        sh[t] = h > 0.f ? h : 0.f;
    }
    __syncthreads();

    #pragma unroll
    for (int k = 0; k < 3; ++k) {             // 768 outputs / 256 threads
        int c = t + k * 256;
        const vfloat4* row = (const vfloat4*)(w2 + (size_t)c * HID_);
        float a0 = 0.f, a1 = 0.f, a2 = 0.f, a3 = 0.f;
        #pragma unroll 2
        for (int f = 0; f < HID_ / 16; ++f) { // 12 iters x 4 float4
            vfloat4 u0 = row[4*f+0], u1 = row[4*f+1], u2 = row[4*f+2], u3 = row[4*f+3];
            const float* hh = &sh[16 * f];
            a0 += u0.x*hh[ 0] + u0.y*hh[ 1] + u0.z*hh[ 2] + u0.w*hh[ 3];
            a1 += u1.x*hh[ 4] + u1.y*hh[ 5] + u1.z*hh[ 6] + u1.w*hh[ 7];
            a2 += u2.x*hh[ 8] + u2.y*hh[ 9] + u2.z*hh[10] + u2.w*hh[11];
            a3 += u3.x*hh[12] + u3.y*hh[13] + u3.z*hh[14] + u3.w*hh[15];
        }
        float z = a0 + a1 + a2 + a3 + b2[c];
        float sg = z * (1.0f / 6.0f) + 0.5f;
        sg = sg < 0.f ? 0.f : (sg > 1.f ? 1.f : sg);
        s_out[b * C_ + c] = sg;
    }
}

// ---------- Kernel 2: out = x * s[b,c], wave-per-channel ----------
// s[wave] is a wave-uniform address -> single broadcast load (no per-thread
// divide / gather). Non-temporal stores keep x L3-resident for the next
// iteration's pool pass.
__global__ __launch_bounds__(256) void scale_kernel(const float* __restrict__ x,
                                                    const float* __restrict__ s,
                                                    float* __restrict__ out) {
    const int wave = (int)((blockIdx.x * 256 + threadIdx.x) >> 6);  // channel idx
    const int lane = threadIdx.x & 63;
    const float sc = s[wave];
    const vfloat4* p = (const vfloat4*)(x + (size_t)wave * HW_);
    vfloat4* q = (vfloat4*)(out + (size_t)wave * HW_);
    vfloat4 v0 = p[lane];
    vfloat4 v1 = p[lane + 64];
    vfloat4 v2 = p[lane + 128];
    __builtin_nontemporal_store(v0 * sc, q + lane);
    __builtin_nontemporal_store(v1 * sc, q + lane + 64);
    __builtin_nontemporal_store(v2 * sc, q + lane + 128);
    if (lane < V4PC - 192) {
        vfloat4 v3 = p[lane + 192];
        __builtin_nontemporal_store(v3 * sc, q + lane + 192);
    }
}

extern "C" void kernel_launch(void* const* d_in, const int* in_sizes, int n_in,
                              void* d_out, int out_size, void* d_ws, size_t ws_size,
                              hipStream_t stream) {
    const float* x  = (const float*)d_in[0];
    const float* w1 = (const float*)d_in[1];
    const float* b1 = (const float*)d_in[2];
    const float* w2 = (const float*)d_in[3];
    const float* b2 = (const float*)d_in[4];
    float* out = (float*)d_out;

    float* pooled = (float*)d_ws;                               // 192 KiB
    float* s      = (float*)d_ws + NCHAN;                       // 192 KiB
    unsigned int* done = (unsigned int*)((float*)d_ws + 2 * NCHAN);  // 256 B

    // workspace is re-poisoned between iterations -> counters must be zeroed
    hipMemsetAsync(done, 0, B_ * sizeof(unsigned int), stream);

    poolfc_kernel<<<PF_BLOCKS, 256, 0, stream>>>(x, w1, b1, w2, b2, pooled, s, done);
    scale_kernel<<<NCHAN / 4, 256, 0, stream>>>(x, s, out);
}

// Round 2
// 423.460 us; speedup vs baseline: 1.2531x; 1.2531x over previous
//
#include <hip/hip_runtime.h>
#include <cstdint>

// Problem constants (x: [64, 768, 28, 28] fp32)
#define B_   64
#define C_   768
#define HID_ 192
#define HW_  784                 // 28*28
#define NCHAN (B_ * C_)          // 49152
#define V4PC (HW_ / 4)           // 196 float4 per channel

typedef float vfloat4 __attribute__((ext_vector_type(4)));

#define PF_BLOCKS 4096
#define CH_PER_BLOCK (NCHAN / PF_BLOCKS)      // 12 channels per block
#define BLK_PER_BATCH (PF_BLOCKS / B_)        // 64 blocks cover one batch image
#define DONE_STRIDE 32                        // 128 B between counters (no line sharing)

// ---------- Kernel 1: fused global-avg-pool + FC1/FC2 (last-arriver, relaxed) ----
// Protocol (NO release/acquire fences — round-1's 313us regression was the
// per-block wbl2 + winner buffer_inv those fences emit on non-coherent XCD L2s):
//   1. pooled[ch] written with RELAXED agent-scope atomic stores (sc1 ->
//      write-through to the coherence point, no cache maintenance).
//   2. __syncthreads() drains vmcnt(0) for every wave (compiler emits full
//      s_waitcnt before s_barrier) -> this block's stores are AT the coherence
//      point before thread 0 issues the counter RMW.
//   3. done[b] RELAXED agent fetch_add. RMWs serialize at the coherence point;
//      the 32nd arriver's later atomic loads of pooled reach the coherence
//      point after all data stores. No buffer_inv -> w1/w2 stay L2-warm.
__global__ __launch_bounds__(256) void poolfc_kernel(
    const float* __restrict__ x,
    const float* __restrict__ w1, const float* __restrict__ b1,
    const float* __restrict__ w2, const float* __restrict__ b2,
    float* __restrict__ pooled, float* __restrict__ s_out,
    unsigned int* __restrict__ done)
{
    const int bid  = blockIdx.x;
    const int t    = threadIdx.x;
    const int wv   = t >> 6;
    const int lane = t & 63;
    const int b    = bid / BLK_PER_BATCH;

    // ---- pool phase: wave-per-channel, 3 channels per wave ----
    for (int i = wv; i < CH_PER_BLOCK; i += 4) {
        const int ch = bid * CH_PER_BLOCK + i;
        const vfloat4* p = (const vfloat4*)(x + (size_t)ch * HW_);
        vfloat4 v0 = p[lane];
        vfloat4 v1 = p[lane + 64];
        vfloat4 v2 = p[lane + 128];
        float sum = (v0.x + v0.y + v0.z + v0.w)
                  + (v1.x + v1.y + v1.z + v1.w)
                  + (v2.x + v2.y + v2.z + v2.w);
        if (lane < V4PC - 192) {              // tail float4 indices 192..195
            vfloat4 v3 = p[lane + 192];
            sum += v3.x + v3.y + v3.z + v3.w;
        }
        #pragma unroll
        for (int off = 32; off > 0; off >>= 1) sum += __shfl_down(sum, off, 64);
        if (lane == 0)
            __hip_atomic_store(&pooled[ch], sum * (1.0f / (float)HW_),
                               __ATOMIC_RELAXED, __HIP_MEMORY_SCOPE_AGENT);
    }
    __syncthreads();   // full waitcnt before s_barrier -> sc1 stores visible

    __shared__ int winner_s;
    if (t == 0) {
        unsigned old = __hip_atomic_fetch_add(&done[b * DONE_STRIDE], 1u,
                                              __ATOMIC_RELAXED,
                                              __HIP_MEMORY_SCOPE_AGENT);
        winner_s = (old == BLK_PER_BATCH - 1);
    }
    __syncthreads();
    if (!winner_s) return;

    // ---- fc phase: this block owns batch b (runs while other batches pool) ----
    __shared__ float sp[C_];
    __shared__ float part[768];
    __shared__ float sh[HID_];
    for (int i = t; i < C_; i += 256)
        sp[i] = __hip_atomic_load(&pooled[b * C_ + i],
                                  __ATOMIC_RELAXED, __HIP_MEMORY_SCOPE_AGENT);
    __syncthreads();

    // FC1: 768 tasks = (hidden h, quarter q); each task = 48 float4 (192 floats)
    #pragma unroll
    for (int k = 0; k < 3; ++k) {
        int task = t + 256 * k;
        int h = task % HID_, q = task / HID_;
        const vfloat4* row = (const vfloat4*)(w1 + (size_t)h * C_) + q * 48;
        const float*   pp  = &sp[q * 192];
        float a0 = 0.f, a1 = 0.f, a2 = 0.f, a3 = 0.f;
        #pragma unroll 3
        for (int f = 0; f < 12; ++f) {
            vfloat4 u0 = row[4*f+0], u1 = row[4*f+1], u2 = row[4*f+2], u3 = row[4*f+3];
            const float* s16 = &pp[16 * f];
            a0 += u0.x*s16[ 0] + u0.y*s16[ 1] + u0.z*s16[ 2] + u0.w*s16[ 3];
            a1 += u1.x*s16[ 4] + u1.y*s16[ 5] + u1.z*s16[ 6] + u1.w*s16[ 7];
            a2 += u2.x*s16[ 8] + u2.y*s16[ 9] + u2.z*s16[10] + u2.w*s16[11];
            a3 += u3.x*s16[12] + u3.y*s16[13] + u3.z*s16[14] + u3.w*s16[15];
        }
        part[q * HID_ + h] = a0 + a1 + a2 + a3;
    }
    __syncthreads();
    if (t < HID_) {
        float hsum = part[t] + part[HID_ + t] + part[2*HID_ + t] + part[3*HID_ + t] + b1[t];
        sh[t] = hsum > 0.f ? hsum : 0.f;
    }
    __syncthreads();

    // FC2: 768 outputs / 256 threads = 3 each; each dot = 48 float4 (192 floats)
    #pragma unroll
    for (int k = 0; k < 3; ++k) {
        int c = t + k * 256;
        const vfloat4* row = (const vfloat4*)(w2 + (size_t)c * HID_);
        float a0 = 0.f, a1 = 0.f, a2 = 0.f, a3 = 0.f;
        #pragma unroll 3
        for (int f = 0; f < 12; ++f) {
            vfloat4 u0 = row[4*f+0], u1 = row[4*f+1], u2 = row[4*f+2], u3 = row[4*f+3];
            const float* hh = &sh[16 * f];
            a0 += u0.x*hh[ 0] + u0.y*hh[ 1] + u0.z*hh[ 2] + u0.w*hh[ 3];
            a1 += u1.x*hh[ 4] + u1.y*hh[ 5] + u1.z*hh[ 6] + u1.w*hh[ 7];
            a2 += u2.x*hh[ 8] + u2.y*hh[ 9] + u2.z*hh[10] + u2.w*hh[11];
            a3 += u3.x*hh[12] + u3.y*hh[13] + u3.z*hh[14] + u3.w*hh[15];
        }
        float z = a0 + a1 + a2 + a3 + b2[c];
        float sg = z * (1.0f / 6.0f) + 0.5f;
        sg = sg < 0.f ? 0.f : (sg > 1.f ? 1.f : sg);
        s_out[b * C_ + c] = sg;
    }
}

// ---------- Kernel 2: out = x * s[b,c], wave-per-channel ----------
__global__ __launch_bounds__(256) void scale_kernel(const float* __restrict__ x,
                                                    const float* __restrict__ s,
                                                    float* __restrict__ out) {
    const int wave = (int)((blockIdx.x * 256 + threadIdx.x) >> 6);  // channel idx
    const int lane = threadIdx.x & 63;
    const float sc = s[wave];
    const vfloat4* p = (const vfloat4*)(x + (size_t)wave * HW_);
    vfloat4* q = (vfloat4*)(out + (size_t)wave * HW_);
    vfloat4 v0 = p[lane];
    vfloat4 v1 = p[lane + 64];
    vfloat4 v2 = p[lane + 128];
    __builtin_nontemporal_store(v0 * sc, q + lane);
    __builtin_nontemporal_store(v1 * sc, q + lane + 64);
    __builtin_nontemporal_store(v2 * sc, q + lane + 128);
    if (lane < V4PC - 192) {
        vfloat4 v3 = p[lane + 192];
        __builtin_nontemporal_store(v3 * sc, q + lane + 192);
    }
}

extern "C" void kernel_launch(void* const* d_in, const int* in_sizes, int n_in,
                              void* d_out, int out_size, void* d_ws, size_t ws_size,
                              hipStream_t stream) {
    const float* x  = (const float*)d_in[0];
    const float* w1 = (const float*)d_in[1];
    const float* b1 = (const float*)d_in[2];
    const float* w2 = (const float*)d_in[3];
    const float* b2 = (const float*)d_in[4];
    float* out = (float*)d_out;

    float* pooled = (float*)d_ws;                                    // 192 KiB
    float* s      = (float*)d_ws + NCHAN;                            // 192 KiB
    unsigned int* done = (unsigned int*)((float*)d_ws + 2 * NCHAN);  // 8 KiB

    // workspace is re-poisoned between iterations -> counters must be zeroed
    hipMemsetAsync(done, 0, B_ * DONE_STRIDE * sizeof(unsigned int), stream);

    poolfc_kernel<<<PF_BLOCKS, 256, 0, stream>>>(x, w1, b1, w2, b2, pooled, s, done);
    scale_kernel<<<NCHAN / 4, 256, 0, stream>>>(x, s, out);
}

// Round 3
// 295.213 us; speedup vs baseline: 1.7975x; 1.4344x over previous
//
#include <hip/hip_runtime.h>
#include <cstdint>

// Problem constants (x: [64, 768, 28, 28] fp32)
#define B_   64
#define C_   768
#define HID_ 192
#define HW_  784                 // 28*28
#define NCHAN (B_ * C_)          // 49152
#define V4PC (HW_ / 4)           // 196 float4 per channel

typedef float vfloat4 __attribute__((ext_vector_type(4)));

// ---------- Kernel 1: global avg pool, wave-per-channel -> pooledT[c][b] ----------
// Transposed output: fc1 reads column b at consecutive lanes -> coalesced 256 B
// wave transactions instead of per-lane 768 B-strided rows.
__global__ __launch_bounds__(256) void pool_kernel(const float* __restrict__ x,
                                                   float* __restrict__ pooledT) {
    const int ch   = (int)((blockIdx.x * 256 + threadIdx.x) >> 6);  // b*C + c
    const int lane = threadIdx.x & 63;
    const vfloat4* p = (const vfloat4*)(x + (size_t)ch * HW_);
    vfloat4 v0 = p[lane];
    vfloat4 v1 = p[lane + 64];
    vfloat4 v2 = p[lane + 128];
    float sum = (v0.x + v0.y + v0.z + v0.w)
              + (v1.x + v1.y + v1.z + v1.w)
              + (v2.x + v2.y + v2.z + v2.w);
    if (lane < V4PC - 192) {                  // tail float4 indices 192..195
        vfloat4 v3 = p[lane + 192];
        sum += v3.x + v3.y + v3.z + v3.w;
    }
    #pragma unroll
    for (int off = 32; off > 0; off >>= 1) sum += __shfl_down(sum, off, 64);
    if (lane == 0) {
        int b = ch / C_, c = ch % C_;
        pooledT[c * B_ + b] = sum * (1.0f / (float)HW_);
    }
}

// ---------- Kernel 2: FC1 + ReLU, weight-stationary over batch ----------
// 192 blocks: block k owns hidden unit k. w1 row k (3 KB) staged in LDS once;
// thread (q = t>>6, b = t&63) dots quarter q of column b. Weights cross the
// fabric ONCE total (not 64x as in the per-batch scheme -- round 2's 77 MB
// FETCH was exactly 64 re-reads of w1+w2 at single-block occupancy).
__global__ __launch_bounds__(256) void fc1_kernel(const float* __restrict__ pooledT,
                                                  const float* __restrict__ w1,
                                                  const float* __restrict__ b1,
                                                  float* __restrict__ hT) {
    __shared__ float w[C_];
    __shared__ float part[4][B_];
    const int k = blockIdx.x;
    const int t = threadIdx.x;
    if (t < C_ / 4) ((vfloat4*)w)[t] = ((const vfloat4*)(w1 + (size_t)k * C_))[t];
    __syncthreads();

    const int q = t >> 6, b = t & 63;
    const float* pc = pooledT + q * 192 * B_ + b;   // column b, rows q*192..+191
    const float* wq = w + q * 192;                  // wave-uniform LDS broadcast
    float a0 = 0.f, a1 = 0.f, a2 = 0.f, a3 = 0.f;
    #pragma unroll 4
    for (int j = 0; j < 192; j += 4) {              // coalesced 256 B wave loads
        a0 += pc[(j + 0) * B_] * wq[j + 0];
        a1 += pc[(j + 1) * B_] * wq[j + 1];
        a2 += pc[(j + 2) * B_] * wq[j + 2];
        a3 += pc[(j + 3) * B_] * wq[j + 3];
    }
    part[q][b] = (a0 + a1) + (a2 + a3);
    __syncthreads();
    if (t < B_) {
        float h = part[0][t] + part[1][t] + part[2][t] + part[3][t] + b1[k];
        hT[k * B_ + t] = h > 0.f ? h : 0.f;         // transposed: coalesced store
    }
}

// ---------- Kernel 3: FC2 + hardsigmoid, weight-stationary over batch ----------
// 192 blocks: block j owns output channels 4j..4j+3. w2 rows (3 KB) in LDS;
// thread (cl = t>>6, b = t&63) dots hT column b (coalesced, 48 KB L2-resident).
__global__ __launch_bounds__(256) void fc2_kernel(const float* __restrict__ hT,
                                                  const float* __restrict__ w2,
                                                  const float* __restrict__ b2,
                                                  float* __restrict__ s_out) {
    __shared__ float w[4 * HID_];
    const int j = blockIdx.x;
    const int t = threadIdx.x;
    if (t < 4 * HID_ / 4)                            // rows 4j..4j+3 are contiguous
        ((vfloat4*)w)[t] = ((const vfloat4*)(w2 + (size_t)j * 4 * HID_))[t];
    __syncthreads();

    const int cl = t >> 6, b = t & 63;
    const float* hc = hT + b;                        // column b of hT
    const float* wc = w + cl * HID_;                 // wave-uniform LDS broadcast
    float a0 = 0.f, a1 = 0.f, a2 = 0.f, a3 = 0.f;
    #pragma unroll 4
    for (int k = 0; k < HID_; k += 4) {
        a0 += hc[(k + 0) * B_] * wc[k + 0];
        a1 += hc[(k + 1) * B_] * wc[k + 1];
        a2 += hc[(k + 2) * B_] * wc[k + 2];
        a3 += hc[(k + 3) * B_] * wc[k + 3];
    }
    float z = (a0 + a1) + (a2 + a3) + b2[j * 4 + cl];
    float sg = z * (1.0f / 6.0f) + 0.5f;
    sg = sg < 0.f ? 0.f : (sg > 1.f ? 1.f : sg);
    s_out[b * C_ + j * 4 + cl] = sg;
}

// ---------- Kernel 4: out = x * s[b,c], wave-per-channel, nt stores ----------
__global__ __launch_bounds__(256) void scale_kernel(const float* __restrict__ x,
                                                    const float* __restrict__ s,
                                                    float* __restrict__ out) {
    const int wave = (int)((blockIdx.x * 256 + threadIdx.x) >> 6);  // b*C + c
    const int lane = threadIdx.x & 63;
    const float sc = s[wave];                        // wave-uniform broadcast
    const vfloat4* p = (const vfloat4*)(x + (size_t)wave * HW_);
    vfloat4* q = (vfloat4*)(out + (size_t)wave * HW_);
    vfloat4 v0 = p[lane];
    vfloat4 v1 = p[lane + 64];
    vfloat4 v2 = p[lane + 128];
    __builtin_nontemporal_store(v0 * sc, q + lane);
    __builtin_nontemporal_store(v1 * sc, q + lane + 64);
    __builtin_nontemporal_store(v2 * sc, q + lane + 128);
    if (lane < V4PC - 192) {
        vfloat4 v3 = p[lane + 192];
        __builtin_nontemporal_store(v3 * sc, q + lane + 192);
    }
}

extern "C" void kernel_launch(void* const* d_in, const int* in_sizes, int n_in,
                              void* d_out, int out_size, void* d_ws, size_t ws_size,
                              hipStream_t stream) {
    const float* x  = (const float*)d_in[0];
    const float* w1 = (const float*)d_in[1];
    const float* b1 = (const float*)d_in[2];
    const float* w2 = (const float*)d_in[3];
    const float* b2 = (const float*)d_in[4];
    float* out = (float*)d_out;

    float* pooledT = (float*)d_ws;                       // C*B fp32 = 192 KiB
    float* hT      = pooledT + C_ * B_;                  // HID*B fp32 = 48 KiB
    float* s       = hT + HID_ * B_;                     // B*C fp32 = 192 KiB

    pool_kernel <<<NCHAN / 4, 256, 0, stream>>>(x, pooledT);
    fc1_kernel  <<<HID_,      256, 0, stream>>>(pooledT, w1, b1, hT);
    fc2_kernel  <<<C_ / 4,    256, 0, stream>>>(hT, w2, b2, s);
    scale_kernel<<<NCHAN / 4, 256, 0, stream>>>(x, s, out);
}

// Round 4
// 293.970 us; speedup vs baseline: 1.8051x; 1.0042x over previous
//
#include <hip/hip_runtime.h>
#include <cstdint>

// Problem constants (x: [64, 768, 28, 28] fp32)
#define B_   64
#define C_   768
#define HID_ 192
#define HW_  784                 // 28*28
#define NCHAN (B_ * C_)          // 49152
#define V4PC (HW_ / 4)           // 196 float4 per channel

typedef float vfloat4 __attribute__((ext_vector_type(4)));

// ---------- Kernel 1: global avg pool, wave-per-channel -> pooledT[c][b] ----------
// Transposed output: fc1 reads column b at consecutive lanes -> coalesced 256 B
// wave transactions instead of per-lane 768 B-strided rows.
__global__ __launch_bounds__(256) void pool_kernel(const float* __restrict__ x,
                                                   float* __restrict__ pooledT) {
    const int ch   = (int)((blockIdx.x * 256 + threadIdx.x) >> 6);  // b*C + c
    const int lane = threadIdx.x & 63;
    const vfloat4* p = (const vfloat4*)(x + (size_t)ch * HW_);
    vfloat4 v0 = p[lane];
    vfloat4 v1 = p[lane + 64];
    vfloat4 v2 = p[lane + 128];
    float sum = (v0.x + v0.y + v0.z + v0.w)
              + (v1.x + v1.y + v1.z + v1.w)
              + (v2.x + v2.y + v2.z + v2.w);
    if (lane < V4PC - 192) {                  // tail float4 indices 192..195
        vfloat4 v3 = p[lane + 192];
        sum += v3.x + v3.y + v3.z + v3.w;
    }
    #pragma unroll
    for (int off = 32; off > 0; off >>= 1) sum += __shfl_down(sum, off, 64);
    if (lane == 0) {
        int b = ch / C_, c = ch % C_;
        pooledT[c * B_ + b] = sum * (1.0f / (float)HW_);
    }
}

// ---------- Kernel 2: FC1 + ReLU, weight-stationary over batch ----------
// 192 blocks: block k owns hidden unit k. w1 row k (3 KB) staged in LDS once;
// thread (q = t>>6, b = t&63) dots quarter q of column b. Weights cross the
// fabric ONCE total (round 2's 77 MB FETCH was 64 re-reads of w1+w2 at
// single-block occupancy -- never batch-per-block for the FC stack).
__global__ __launch_bounds__(256) void fc1_kernel(const float* __restrict__ pooledT,
                                                  const float* __restrict__ w1,
                                                  const float* __restrict__ b1,
                                                  float* __restrict__ hT) {
    __shared__ float w[C_];
    __shared__ float part[4][B_];
    const int k = blockIdx.x;
    const int t = threadIdx.x;
    if (t < C_ / 4) ((vfloat4*)w)[t] = ((const vfloat4*)(w1 + (size_t)k * C_))[t];
    __syncthreads();

    const int q = t >> 6, b = t & 63;
    const float* pc = pooledT + q * 192 * B_ + b;   // column b, rows q*192..+191
    const float* wq = w + q * 192;                  // wave-uniform LDS broadcast
    float a0 = 0.f, a1 = 0.f, a2 = 0.f, a3 = 0.f;
    #pragma unroll 4
    for (int j = 0; j < 192; j += 4) {              // coalesced 256 B wave loads
        a0 += pc[(j + 0) * B_] * wq[j + 0];
        a1 += pc[(j + 1) * B_] * wq[j + 1];
        a2 += pc[(j + 2) * B_] * wq[j + 2];
        a3 += pc[(j + 3) * B_] * wq[j + 3];
    }
    part[q][b] = (a0 + a1) + (a2 + a3);
    __syncthreads();
    if (t < B_) {
        float h = part[0][t] + part[1][t] + part[2][t] + part[3][t] + b1[k];
        hT[k * B_ + t] = h > 0.f ? h : 0.f;         // transposed: coalesced store
    }
}

// ---------- Kernel 3: FC2 + hardsigmoid + scale, fused ----------
// One block per output channel c (768 blocks). Prologue (~3 us): thread
// (q = t>>6, b = t&63) dots quarter q of hT column b against w2 row c (LDS),
// LDS-reduce 4 partials -> 64 gates in LDS. Then the block streams its 64
// channel-images: wave w scales batches 16w..16w+15 (coalesced 1 KB wave
// loads, non-temporal stores so the write stream doesn't evict L3-warm x).
// Removes the separate fc2 dispatch + gap and the s[] round-trip.
__global__ __launch_bounds__(256) void fc2scale_kernel(const float* __restrict__ hT,
                                                       const float* __restrict__ w2,
                                                       const float* __restrict__ b2,
                                                       const float* __restrict__ x,
                                                       float* __restrict__ out) {
    __shared__ float w[HID_];
    __shared__ float part[4][B_];
    __shared__ float gate[B_];
    const int c = blockIdx.x;
    const int t = threadIdx.x;
    if (t < HID_ / 4)
        ((vfloat4*)w)[t] = ((const vfloat4*)(w2 + (size_t)c * HID_))[t];
    __syncthreads();

    {   // FC2 dot: quarter q (48 floats) of column b
        const int q = t >> 6, b = t & 63;
        const float* hc = hT + q * 48 * B_ + b;     // coalesced: lane = batch
        const float* wq = w + q * 48;               // wave-uniform LDS broadcast
        float a0 = 0.f, a1 = 0.f, a2 = 0.f, a3 = 0.f;
        #pragma unroll 4
        for (int k = 0; k < 48; k += 4) {
            a0 += hc[(k + 0) * B_] * wq[k + 0];
            a1 += hc[(k + 1) * B_] * wq[k + 1];
            a2 += hc[(k + 2) * B_] * wq[k + 2];
            a3 += hc[(k + 3) * B_] * wq[k + 3];
        }
        part[q][b] = (a0 + a1) + (a2 + a3);
    }
    __syncthreads();
    if (t < B_) {
        float z = part[0][t] + part[1][t] + part[2][t] + part[3][t] + b2[c];
        float sg = z * (1.0f / 6.0f) + 0.5f;
        gate[t] = sg < 0.f ? 0.f : (sg > 1.f ? 1.f : sg);
    }
    __syncthreads();

    // scale phase: 4 waves x 16 batches each
    const int wv = t >> 6, lane = t & 63;
    for (int bb = wv * 16; bb < wv * 16 + 16; ++bb) {
        const float sc = gate[bb];                  // uniform LDS broadcast
        const vfloat4* p = (const vfloat4*)(x + ((size_t)bb * C_ + c) * HW_);
        vfloat4* qo = (vfloat4*)(out + ((size_t)bb * C_ + c) * HW_);
        vfloat4 v0 = p[lane];
        vfloat4 v1 = p[lane + 64];
        vfloat4 v2 = p[lane + 128];
        __builtin_nontemporal_store(v0 * sc, qo + lane);
        __builtin_nontemporal_store(v1 * sc, qo + lane + 64);
        __builtin_nontemporal_store(v2 * sc, qo + lane + 128);
        if (lane < V4PC - 192) {                    // tail float4 192..195
            vfloat4 v3 = p[lane + 192];
            __builtin_nontemporal_store(v3 * sc, qo + lane + 192);
        }
    }
}

extern "C" void kernel_launch(void* const* d_in, const int* in_sizes, int n_in,
                              void* d_out, int out_size, void* d_ws, size_t ws_size,
                              hipStream_t stream) {
    const float* x  = (const float*)d_in[0];
    const float* w1 = (const float*)d_in[1];
    const float* b1 = (const float*)d_in[2];
    const float* w2 = (const float*)d_in[3];
    const float* b2 = (const float*)d_in[4];
    float* out = (float*)d_out;

    float* pooledT = (float*)d_ws;                       // C*B fp32 = 192 KiB
    float* hT      = pooledT + C_ * B_;                  // HID*B fp32 = 48 KiB

    pool_kernel    <<<NCHAN / 4, 256, 0, stream>>>(x, pooledT);
    fc1_kernel     <<<HID_,      256, 0, stream>>>(pooledT, w1, b1, hT);
    fc2scale_kernel<<<C_,        256, 0, stream>>>(hT, w2, b2, x, out);
}

// Round 5
// 290.467 us; speedup vs baseline: 1.8268x; 1.0121x over previous
//
#include <hip/hip_runtime.h>
#include <cstdint>

// Problem constants (x: [64, 768, 28, 28] fp32)
#define B_   64
#define C_   768
#define HID_ 192
#define HW_  784                 // 28*28
#define NCHAN (B_ * C_)          // 49152
#define V4PC (HW_ / 4)           // 196 float4 per channel

typedef float vfloat4 __attribute__((ext_vector_type(4)));

// ---------- Kernel 1: global avg pool, wave-per-channel -> pooledT[c][b] ----------
// Transposed output: fc1 reads column b at consecutive lanes -> coalesced 256 B
// wave transactions instead of per-lane 768 B-strided rows.
__global__ __launch_bounds__(256) void pool_kernel(const float* __restrict__ x,
                                                   float* __restrict__ pooledT) {
    const int ch   = (int)((blockIdx.x * 256 + threadIdx.x) >> 6);  // b*C + c
    const int lane = threadIdx.x & 63;
    const vfloat4* p = (const vfloat4*)(x + (size_t)ch * HW_);
    vfloat4 v0 = p[lane];
    vfloat4 v1 = p[lane + 64];
    vfloat4 v2 = p[lane + 128];
    float sum = (v0.x + v0.y + v0.z + v0.w)
              + (v1.x + v1.y + v1.z + v1.w)
              + (v2.x + v2.y + v2.z + v2.w);
    if (lane < V4PC - 192) {                  // tail float4 indices 192..195
        vfloat4 v3 = p[lane + 192];
        sum += v3.x + v3.y + v3.z + v3.w;
    }
    #pragma unroll
    for (int off = 32; off > 0; off >>= 1) sum += __shfl_down(sum, off, 64);
    if (lane == 0) {
        int b = ch / C_, c = ch % C_;
        pooledT[c * B_ + b] = sum * (1.0f / (float)HW_);
    }
}

// ---------- Kernel 2: FC1 + ReLU, weight-stationary over batch ----------
// 192 blocks: block k owns hidden unit k. w1 row k (3 KB) staged in LDS once;
// thread (q = t>>6, b = t&63) dots quarter q of column b. Weights cross the
// fabric ONCE total (round 2's 77 MB FETCH was 64 re-reads of w1+w2 at
// single-block occupancy -- never batch-per-block for the FC stack).
__global__ __launch_bounds__(256) void fc1_kernel(const float* __restrict__ pooledT,
                                                  const float* __restrict__ w1,
                                                  const float* __restrict__ b1,
                                                  float* __restrict__ hT) {
    __shared__ float w[C_];
    __shared__ float part[4][B_];
    const int k = blockIdx.x;
    const int t = threadIdx.x;
    if (t < C_ / 4) ((vfloat4*)w)[t] = ((const vfloat4*)(w1 + (size_t)k * C_))[t];
    __syncthreads();

    const int q = t >> 6, b = t & 63;
    const float* pc = pooledT + q * 192 * B_ + b;   // column b, rows q*192..+191
    const float* wq = w + q * 192;                  // wave-uniform LDS broadcast
    float a0 = 0.f, a1 = 0.f, a2 = 0.f, a3 = 0.f;
    #pragma unroll 4
    for (int j = 0; j < 192; j += 4) {              // coalesced 256 B wave loads
        a0 += pc[(j + 0) * B_] * wq[j + 0];
        a1 += pc[(j + 1) * B_] * wq[j + 1];
        a2 += pc[(j + 2) * B_] * wq[j + 2];
        a3 += pc[(j + 3) * B_] * wq[j + 3];
    }
    part[q][b] = (a0 + a1) + (a2 + a3);
    __syncthreads();
    if (t < B_) {
        float h = part[0][t] + part[1][t] + part[2][t] + part[3][t] + b1[k];
        hT[k * B_ + t] = h > 0.f ? h : 0.f;         // transposed: coalesced store
    }
}

// ---------- Kernel 3: FC2 + hardsigmoid + scale, fused, batch-split for TLP ----
// Grid 768 x 4: block (c, g) gates and streams batches 16g..16g+15 of channel c.
// Round-4 version ran 768 blocks x 16 serial batch-images per wave = 3 waves/SIMD
// exposed to a full load-latency round trip per image; 4x more blocks puts 4x
// more waves in flight during the streaming phase (the latency-bound part).
// Prologue: thread (p = t>>4, bl = t&15) dots K-segment p (12 floats) of hT
// column (16g+bl) against w2 row c (LDS); 16-way LDS reduce -> 16 gates.
__global__ __launch_bounds__(256) void fc2scale_kernel(const float* __restrict__ hT,
                                                       const float* __restrict__ w2,
                                                       const float* __restrict__ b2,
                                                       const float* __restrict__ x,
                                                       float* __restrict__ out) {
    __shared__ float w[HID_];
    __shared__ float part[16][16];
    __shared__ float gate[16];
    const int c = blockIdx.x >> 2;
    const int g = blockIdx.x & 3;
    const int t = threadIdx.x;
    if (t < HID_ / 4)
        ((vfloat4*)w)[t] = ((const vfloat4*)(w2 + (size_t)c * HID_))[t];
    __syncthreads();

    {   // FC2 dot: K-segment p (12 floats) of column (16g + bl)
        const int p = t >> 4, bl = t & 15;
        const float* hc = hT + p * 12 * B_ + g * 16 + bl;
        const float* wp = w + p * 12;
        float a0 = 0.f, a1 = 0.f, a2 = 0.f;
        #pragma unroll
        for (int j = 0; j < 12; j += 3) {
            a0 += hc[(j + 0) * B_] * wp[j + 0];
            a1 += hc[(j + 1) * B_] * wp[j + 1];
            a2 += hc[(j + 2) * B_] * wp[j + 2];
        }
        part[p][bl] = (a0 + a1) + a2;
    }
    __syncthreads();
    if (t < 16) {
        float z = b2[c];
        #pragma unroll
        for (int p = 0; p < 16; ++p) z += part[p][t];
        float sg = z * (1.0f / 6.0f) + 0.5f;
        gate[t] = sg < 0.f ? 0.f : (sg > 1.f ? 1.f : sg);
    }
    __syncthreads();

    // scale phase: 4 waves x 4 batch-images each
    const int wv = t >> 6, lane = t & 63;
    #pragma unroll
    for (int i = 0; i < 4; ++i) {
        const int bl = wv * 4 + i;                  // local batch 0..15
        const float sc = gate[bl];                  // uniform LDS broadcast
        const size_t chan = (size_t)(g * 16 + bl) * C_ + c;
        const vfloat4* p = (const vfloat4*)(x + chan * HW_);
        vfloat4* qo = (vfloat4*)(out + chan * HW_);
        vfloat4 v0 = p[lane];
        vfloat4 v1 = p[lane + 64];
        vfloat4 v2 = p[lane + 128];
        __builtin_nontemporal_store(v0 * sc, qo + lane);
        __builtin_nontemporal_store(v1 * sc, qo + lane + 64);
        __builtin_nontemporal_store(v2 * sc, qo + lane + 128);
        if (lane < V4PC - 192) {                    // tail float4 192..195
            vfloat4 v3 = p[lane + 192];
            __builtin_nontemporal_store(v3 * sc, qo + lane + 192);
        }
    }
}

extern "C" void kernel_launch(void* const* d_in, const int* in_sizes, int n_in,
                              void* d_out, int out_size, void* d_ws, size_t ws_size,
                              hipStream_t stream) {
    const float* x  = (const float*)d_in[0];
    const float* w1 = (const float*)d_in[1];
    const float* b1 = (const float*)d_in[2];
    const float* w2 = (const float*)d_in[3];
    const float* b2 = (const float*)d_in[4];
    float* out = (float*)d_out;

    float* pooledT = (float*)d_ws;                       // C*B fp32 = 192 KiB
    float* hT      = pooledT + C_ * B_;                  // HID*B fp32 = 48 KiB

    pool_kernel    <<<NCHAN / 4, 256, 0, stream>>>(x, pooledT);
    fc1_kernel     <<<HID_,      256, 0, stream>>>(pooledT, w1, b1, hT);
    fc2scale_kernel<<<C_ * 4,    256, 0, stream>>>(hT, w2, b2, x, out);
}